// Round 1
// baseline (664.590 us; speedup 1.0000x reference)
//
#include <hip/hip_runtime.h>
#include <math.h>

#define SMOOTH 0.1f
#define PAD_IDX 0

// Per-row single HBM pass: sum(x) and sum(exp2(x*log2e - BIAS2)).
// lse = BIAS + ln2*log2(sumexp)   (BIAS=4: safe for |x|<~90, same result)
// kld_row = C - (s/V)*(sum_x - V*lse) - (1-s)*(pred[tgt] - lse)
// C = (V-1)*(s/V)*log(s/V) + (1-s+s/V)*log(1-s+s/V)   (row-independent)
//
// R1 change vs 666us baseline: 4-deep float4 load batching (was 2-deep) to
// double per-wave outstanding loads — theory: kernel is HBM-latency-bound
// (787 GB/s achieved vs 6.3 TB/s ceiling), not BW-bound.
__global__ void __launch_bounds__(256)
row_kernel(const float* __restrict__ pred,
           const int* __restrict__ target,
           float* __restrict__ ws, int V) {
    const int row = blockIdx.x;
    const int tid = threadIdx.x;
    const float* __restrict__ p = pred + (long long)row * V;
    const int tgt = target[row];

    const float L2E   = 1.4426950408889634f;   // log2(e)
    const float BIAS  = 4.0f;
    const float BIAS2 = BIAS * L2E;

#define EXP4(v) ( __builtin_amdgcn_exp2f(fmaf((v).x, L2E, -BIAS2)) \
                + __builtin_amdgcn_exp2f(fmaf((v).y, L2E, -BIAS2)) \
                + __builtin_amdgcn_exp2f(fmaf((v).z, L2E, -BIAS2)) \
                + __builtin_amdgcn_exp2f(fmaf((v).w, L2E, -BIAS2)) )
#define SUM4(v) (((v).x + (v).y) + ((v).z + (v).w))

    // four independent accumulator pairs -> no loop-carried serial chain
    float s0 = 0.0f, s1 = 0.0f, s2 = 0.0f, s3 = 0.0f;  // sum exp2(x*L2E - BIAS2)
    float x0 = 0.0f, x1 = 0.0f, x2 = 0.0f, x3 = 0.0f;  // sum x

    const int V4 = V >> 2;
    const float4* __restrict__ p4 = (const float4*)p;

    int i = tid;
    // main loop: 4 float4 loads in flight per thread per iteration
    for (; i + 768 < V4; i += 1024) {
        float4 a = p4[i];
        float4 b = p4[i + 256];
        float4 c = p4[i + 512];
        float4 d = p4[i + 768];
        x0 += SUM4(a);
        x1 += SUM4(b);
        x2 += SUM4(c);
        x3 += SUM4(d);
        s0 += EXP4(a);
        s1 += EXP4(b);
        s2 += EXP4(c);
        s3 += EXP4(d);
    }
    // remainder: single-batch stride-256 (covers every remaining slot;
    // all per-thread indices remain tid + 256*m, so coverage is exact)
    for (; i < V4; i += 256) {
        float4 a = p4[i];
        x0 += SUM4(a);
        s0 += EXP4(a);
    }
    // generic scalar tail (none for V=32000)
    for (int j = (V4 << 2) + tid; j < V; j += 256) {
        float x = p[j];
        x0 += x;
        s0 += __builtin_amdgcn_exp2f(fmaf(x, L2E, -BIAS2));
    }

    float s  = (s0 + s1) + (s2 + s3);
    float sx = (x0 + x1) + (x2 + x3);

    // wave(64) reduce — plain sums, no max merge
    for (int off = 32; off > 0; off >>= 1) {
        s  += __shfl_down(s, off, 64);
        sx += __shfl_down(sx, off, 64);
    }

    __shared__ float ss[4], sxs[4];
    const int wid = tid >> 6, lane = tid & 63;
    if (lane == 0) { ss[wid] = s; sxs[wid] = sx; }
    __syncthreads();

    if (tid == 0) {
        for (int w = 1; w < 4; ++w) { s += ss[w]; sx += sxs[w]; }
        const float LN2 = 0.6931471805599453f;
        float lse = BIAS + LN2 * __builtin_amdgcn_logf(s);  // v_log_f32 = log2
        float pt = p[tgt];   // L2-hot after the streaming pass

        double lo = (double)SMOOTH / (double)V;
        double hi = 1.0 - (double)SMOOTH + lo;
        float C = (float)((double)(V - 1) * lo * log(lo) + hi * log(hi));

        float sum_logp = sx - (float)V * lse;
        float kld = C - (SMOOTH / (float)V) * sum_logp
                      - (1.0f - SMOOTH) * (pt - lse);
        float mask = (tgt != PAD_IDX) ? 1.0f : 0.0f;
        float2 o; o.x = kld * mask; o.y = mask;
        ((float2*)ws)[row] = o;
    }
#undef EXP4
#undef SUM4
}

__global__ void __launch_bounds__(256)
reduce_kernel(const float* __restrict__ ws, float* __restrict__ out, int rows) {
    const int tid = threadIdx.x;
    const float2* __restrict__ w2 = (const float2*)ws;
    float sk = 0.0f, sm = 0.0f;
    for (int i = tid; i < rows; i += 256) {
        float2 v = w2[i];
        sk += v.x;
        sm += v.y;
    }
    for (int off = 32; off > 0; off >>= 1) {
        sk += __shfl_down(sk, off, 64);
        sm += __shfl_down(sm, off, 64);
    }
    __shared__ float a[4], b[4];
    const int wid = tid >> 6, lane = tid & 63;
    if (lane == 0) { a[wid] = sk; b[wid] = sm; }
    __syncthreads();
    if (tid == 0) {
        for (int w = 1; w < 4; ++w) { sk += a[w]; sm += b[w]; }
        out[0] = sk / sm;
    }
}

extern "C" void kernel_launch(void* const* d_in, const int* in_sizes, int n_in,
                              void* d_out, int out_size, void* d_ws, size_t ws_size,
                              hipStream_t stream) {
    const float* pred  = (const float*)d_in[0];
    const int*  target = (const int*)d_in[1];
    const int rows = in_sizes[1];            // B*S = 4096
    const int V    = in_sizes[0] / rows;     // 32000
    float* ws  = (float*)d_ws;               // 2 floats per row
    float* out = (float*)d_out;

    hipLaunchKernelGGL(row_kernel, dim3(rows), dim3(256), 0, stream,
                       pred, target, ws, V);
    hipLaunchKernelGGL(reduce_kernel, dim3(1), dim3(256), 0, stream,
                       ws, out, rows);
}

// Round 2
// 630.045 us; speedup vs baseline: 1.0548x; 1.0548x over previous
//
#include <hip/hip_runtime.h>
#include <math.h>

#define SMOOTH 0.1f
#define PAD_IDX 0

// R2 experiment: row phase measured ~330us (1.6 TB/s) by decomposition
// (dur 664 = harness fill 327 + row ~330 + reduce ~5).
// Changes: (1) 2 column-chunk blocks per row (2x streams, half tail),
// (2) all per-row lse/kld math moved to reduce_kernel, (3) nontemporal
// loads (streaming, zero reuse), (4) tail keeps 4-deep MLP via unroll.
// Math unchanged: per chunk partials {sum_exp2(x*L2E-BIAS2), sum_x, pt}.

typedef float f32x4 __attribute__((ext_vector_type(4)));

__global__ void __launch_bounds__(256)
row_kernel(const float* __restrict__ pred,
           const int* __restrict__ target,
           float* __restrict__ ws, int V) {
    const int row   = blockIdx.x >> 1;
    const int chunk = blockIdx.x & 1;
    const int tid   = threadIdx.x;
    const float* __restrict__ p = pred + (long long)row * V;
    const int tgt = target[row];

    const float L2E   = 1.4426950408889634f;   // log2(e)
    const float BIAS  = 4.0f;
    const float BIAS2 = BIAS * L2E;

    const int V4   = V >> 2;          // 8000
    const int C4   = V4 >> 1;         // 4000 f4 per chunk
    const int base = chunk * C4;
    const int n    = chunk ? (V4 - C4) : C4;
    const f32x4* __restrict__ p4 = ((const f32x4*)p) + base;

    // fetch pred[tgt] early (one thread of the owning chunk) — latency
    // fully hidden under the streaming loop
    float ptv = 0.0f;
    const bool owner = chunk ? (tgt >= 4 * C4) : (tgt < 4 * C4);
    if (owner && tid == 0) ptv = p[tgt];

#define EXP4(v) ( __builtin_amdgcn_exp2f(fmaf((v).x, L2E, -BIAS2)) \
                + __builtin_amdgcn_exp2f(fmaf((v).y, L2E, -BIAS2)) \
                + __builtin_amdgcn_exp2f(fmaf((v).z, L2E, -BIAS2)) \
                + __builtin_amdgcn_exp2f(fmaf((v).w, L2E, -BIAS2)) )
#define SUM4(v) (((v).x + (v).y) + ((v).z + (v).w))

    float s0 = 0.0f, s1 = 0.0f, s2 = 0.0f, s3 = 0.0f;  // sum exp2
    float x0 = 0.0f, x1 = 0.0f, x2 = 0.0f, x3 = 0.0f;  // sum x

    int k = tid;
    for (; k + 768 < n; k += 1024) {
        f32x4 a = __builtin_nontemporal_load(p4 + k);
        f32x4 b = __builtin_nontemporal_load(p4 + k + 256);
        f32x4 c = __builtin_nontemporal_load(p4 + k + 512);
        f32x4 d = __builtin_nontemporal_load(p4 + k + 768);
        x0 += SUM4(a);
        x1 += SUM4(b);
        x2 += SUM4(c);
        x3 += SUM4(d);
        s0 += EXP4(a);
        s1 += EXP4(b);
        s2 += EXP4(c);
        s3 += EXP4(d);
    }
    // tail: keep loads batched 4-deep via unroll
#pragma unroll 4
    for (; k < n; k += 256) {
        f32x4 a = __builtin_nontemporal_load(p4 + k);
        x0 += SUM4(a);
        s0 += EXP4(a);
    }
    // scalar tail for V % 4 != 0 (none at V=32000) — chunk 1 owns it
    if (chunk) {
        for (int j = (V4 << 2) + tid; j < V; j += 256) {
            float x = p[j];
            x0 += x;
            s0 += __builtin_amdgcn_exp2f(fmaf(x, L2E, -BIAS2));
        }
    }

    float s  = (s0 + s1) + (s2 + s3);
    float sx = (x0 + x1) + (x2 + x3);

    // wave(64) reduce
    for (int off = 32; off > 0; off >>= 1) {
        s  += __shfl_down(s, off, 64);
        sx += __shfl_down(sx, off, 64);
    }

    __shared__ float ss[4], sxs[4];
    const int wid = tid >> 6, lane = tid & 63;
    if (lane == 0) { ss[wid] = s; sxs[wid] = sx; }
    __syncthreads();

    if (tid == 0) {
        for (int w = 1; w < 4; ++w) { s += ss[w]; sx += sxs[w]; }
        float mask = (tgt != PAD_IDX) ? 1.0f : 0.0f;
        f32x4 o; o.x = s; o.y = sx; o.z = ptv; o.w = mask;
        ((f32x4*)ws)[blockIdx.x] = o;
    }
#undef EXP4
#undef SUM4
}

// one block, 1024 threads: per-row finalize (lse + kld) + global sum
__global__ void __launch_bounds__(1024)
reduce_kernel(const float* __restrict__ ws, float* __restrict__ out,
              int rows, int V) {
    const int tid = threadIdx.x;
    const f32x4* __restrict__ w4 = (const f32x4*)ws;

    const float BIAS = 4.0f;
    const float LN2  = 0.6931471805599453f;
    double lo = (double)SMOOTH / (double)V;
    double hi = 1.0 - (double)SMOOTH + lo;
    const float C = (float)((double)(V - 1) * lo * log(lo) + hi * log(hi));

    float sk = 0.0f, sm = 0.0f;
    for (int r = tid; r < rows; r += 1024) {
        f32x4 a = w4[2 * r];
        f32x4 b = w4[2 * r + 1];
        float s    = a.x + b.x;
        float sx   = a.y + b.y;
        float pt   = a.z + b.z;     // non-owner wrote 0
        float mask = a.w;
        float lse = BIAS + LN2 * __builtin_amdgcn_logf(s);  // v_log_f32 = log2
        float sum_logp = sx - (float)V * lse;
        float kld = C - (SMOOTH / (float)V) * sum_logp
                      - (1.0f - SMOOTH) * (pt - lse);
        sk += kld * mask;
        sm += mask;
    }
    for (int off = 32; off > 0; off >>= 1) {
        sk += __shfl_down(sk, off, 64);
        sm += __shfl_down(sm, off, 64);
    }
    __shared__ float a16[16], b16[16];
    const int wid = tid >> 6, lane = tid & 63;
    if (lane == 0) { a16[wid] = sk; b16[wid] = sm; }
    __syncthreads();
    if (tid == 0) {
        for (int w = 1; w < 16; ++w) { sk += a16[w]; sm += b16[w]; }
        out[0] = sk / sm;
    }
}

extern "C" void kernel_launch(void* const* d_in, const int* in_sizes, int n_in,
                              void* d_out, int out_size, void* d_ws, size_t ws_size,
                              hipStream_t stream) {
    const float* pred  = (const float*)d_in[0];
    const int*  target = (const int*)d_in[1];
    const int rows = in_sizes[1];            // B*S = 4096
    const int V    = in_sizes[0] / rows;     // 32000
    float* ws  = (float*)d_ws;               // float4 per (row,chunk)
    float* out = (float*)d_out;

    hipLaunchKernelGGL(row_kernel, dim3(rows * 2), dim3(256), 0, stream,
                       pred, target, ws, V);
    hipLaunchKernelGGL(reduce_kernel, dim3(1), dim3(1024), 0, stream,
                       ws, out, rows, V);
}